// Round 6
// baseline (2531.769 us; speedup 1.0000x reference)
//
#include <hip/hip_runtime.h>

#define HID 128
#define SB 1024

// NOTE (harness contract): integer inputs arrive as int32 — edge_index and
// batch MUST be read as const int* (int64 cast was the round-3 core dump).

// ---------------- CSR build ----------------
__global__ void k_hist(const int* __restrict__ dst, int* __restrict__ deg, int e) {
    int i = blockIdx.x * blockDim.x + threadIdx.x;
    if (i < e) atomicAdd(&deg[dst[i]], 1);
}

// phase 1: block-local scan; rs[i] = exclusive prefix within block; partials[b] = block sum
__global__ __launch_bounds__(SB)
void k_scan1(const int* __restrict__ deg, int* __restrict__ rs,
             int* __restrict__ partials, int n) {
    __shared__ int sh[SB];
    int t = threadIdx.x;
    int i = blockIdx.x * SB + t;
    int v = (i < n) ? deg[i] : 0;
    sh[t] = v;
    __syncthreads();
    for (int off = 1; off < SB; off <<= 1) {
        int add = (t >= off) ? sh[t - off] : 0;
        __syncthreads();
        sh[t] += add;
        __syncthreads();
    }
    if (i < n) rs[i] = sh[t] - v;
    if (t == SB - 1) partials[blockIdx.x] = sh[t];
}

// phase 2: single-block exclusive scan of <=256 partials; writes rs[n] = total (=E)
__global__ __launch_bounds__(256)
void k_scan2(int* __restrict__ partials, int* __restrict__ rs, int nb, int n) {
    __shared__ int sh[256];
    int t = threadIdx.x;
    int v = (t < nb) ? partials[t] : 0;
    sh[t] = v;
    __syncthreads();
    for (int off = 1; off < 256; off <<= 1) {
        int add = (t >= off) ? sh[t - off] : 0;
        __syncthreads();
        sh[t] += add;
        __syncthreads();
    }
    if (t < nb) partials[t] = sh[t] - v;  // exclusive block offset
    if (t == 255) rs[n] = sh[t];          // grand total
}

// phase 3: add block offsets; cur = rs
__global__ __launch_bounds__(SB)
void k_scan3(int* __restrict__ rs, int* __restrict__ cur,
             const int* __restrict__ partials, int n) {
    int i = blockIdx.x * SB + threadIdx.x;
    if (i < n) {
        int v = rs[i] + partials[blockIdx.x];
        rs[i] = v;
        cur[i] = v;
    }
}

// XCD-windowed scatter: class p = blockIdx%8 (round-robin -> one XCD) handles only
// dst in window p. That window's CSR range (~800KB, contiguous since csr is laid out
// by rs[]) stays resident in ONE XCD L2 until fully written -> full-line evictions
// instead of 16x partial-line write amplification (R5: WRITE_SIZE was 103MB for 6.4MB).
__global__ __launch_bounds__(256)
void k_scatter(const int* __restrict__ src, const int* __restrict__ dst,
               int* __restrict__ cur, int* __restrict__ csr, int e, int nwin) {
    int p = blockIdx.x & 7;
    int slot = blockIdx.x >> 3;
    int nslots = gridDim.x >> 3;
    int lo = p * nwin, hi = lo + nwin;
    int stride = nslots * blockDim.x;
    for (int i = slot * blockDim.x + threadIdx.x; i < e; i += stride) {
        int d = dst[i];
        if (d >= lo && d < hi) {
            int pos = atomicAdd(&cur[d], 1);  // device-scope, memory-side
            csr[pos] = src[i];
        }
    }
}

// ---------------- gather-aggregate: agg[i] = x[i] + sum_{j in CSR[i]} x[j] ----------------
__global__ __launch_bounds__(256)
void k_gather(const float* __restrict__ x, const int* __restrict__ rs,
              const int* __restrict__ csr, float* __restrict__ agg, int n) {
    int wave = (blockIdx.x * blockDim.x + threadIdx.x) >> 6;
    int lane = threadIdx.x & 63;
    if (wave >= n) return;
    int beg = rs[wave], end = rs[wave + 1];
    const float2* xp = reinterpret_cast<const float2*>(x);
    float2 acc = xp[(size_t)wave * 64 + lane];
    int j = beg;
    for (; j + 4 <= end; j += 4) {
        int s0 = csr[j], s1 = csr[j + 1], s2 = csr[j + 2], s3 = csr[j + 3];
        float2 v0 = xp[(size_t)s0 * 64 + lane];
        float2 v1 = xp[(size_t)s1 * 64 + lane];
        float2 v2 = xp[(size_t)s2 * 64 + lane];
        float2 v3 = xp[(size_t)s3 * 64 + lane];
        acc.x += (v0.x + v1.x) + (v2.x + v3.x);
        acc.y += (v0.y + v1.y) + (v2.y + v3.y);
    }
    for (; j < end; ++j) {
        int s = csr[j];
        float2 v = xp[(size_t)s * 64 + lane];
        acc.x += v.x;
        acc.y += v.y;
    }
    reinterpret_cast<float2*>(agg)[(size_t)wave * 64 + lane] = acc;
}

// ---------------- tiled fp32 GEMM: out[r][c] = A[r][:] . W[:][c] + bias[c] ----------------
// Block = 256 thr = 4 waves, 64-row tile, grid.y = column half.
// A tile staged in LDS (coalesced float4); inner loop reads A via wave-uniform
// ds_read_b128 broadcast (conflict-free); W column in 128 VGPRs/lane.
// BN_LOAD: apply scale/shift+ReLU while staging (bit-identical to the old bnapply pass).
// BN_STATS: f64 per-wave partials -> LDS cross-wave reduce -> 1 atomic/col/block.
// FUSE_OUT: out = relu(acc+bias) + xres.
template <bool BN_STATS, bool BN_LOAD, bool FUSE_OUT>
__global__ __launch_bounds__(256, 2)
void k_gemm(const float* __restrict__ A, const float* __restrict__ W,
            const float* __restrict__ bias, float* __restrict__ out,
            const float* __restrict__ xres,
            const float* __restrict__ bn_scale, const float* __restrict__ bn_shift,
            double* __restrict__ bn_sum, double* __restrict__ bn_sq, int nrows) {
    __shared__ float As[64 * HID];  // 32KB
    int t = threadIdx.x;
    int wid = t >> 6, lane = t & 63;
    int col = blockIdx.y * 64 + lane;
    int row0 = blockIdx.x * 64;
    int nr = min(64, nrows - row0);

    // W column into VGPRs (coalesced 256B per k)
    float w[HID];
#pragma unroll
    for (int k = 0; k < HID; ++k) w[k] = W[k * HID + col];
    float b = bias[col];

    // stage A tile (2048 float4, 8 per thread), optional BN+ReLU on load
    {
        const float4* a4 = reinterpret_cast<const float4*>(A + (size_t)row0 * HID);
        const float4* sc4 = reinterpret_cast<const float4*>(bn_scale);
        const float4* sh4 = reinterpret_cast<const float4*>(bn_shift);
        float4* s4 = reinterpret_cast<float4*>(As);
        int maxv = nr * (HID / 4);
#pragma unroll
        for (int i = 0; i < 8; ++i) {
            int idx = t + 256 * i;
            float4 v = make_float4(0.f, 0.f, 0.f, 0.f);
            if (idx < maxv) v = a4[idx];
            if (BN_LOAD) {
                int c4 = idx & 31;  // float4-group within the 128-wide row
                float4 a = sc4[c4], bb = sh4[c4];
                v.x = fmaxf(fmaf(v.x, a.x, bb.x), 0.f);
                v.y = fmaxf(fmaf(v.y, a.y, bb.y), 0.f);
                v.z = fmaxf(fmaf(v.z, a.z, bb.z), 0.f);
                v.w = fmaxf(fmaf(v.w, a.w, bb.w), 0.f);
            }
            s4[idx] = v;
        }
    }
    __syncthreads();

    double s0 = 0.0, s1 = 0.0;
    for (int rr = wid; rr < nr; rr += 4) {
        const float4* as4 = reinterpret_cast<const float4*>(As + rr * HID);
        float acc0 = 0.f, acc1 = 0.f, acc2 = 0.f, acc3 = 0.f;
#pragma unroll
        for (int kk = 0; kk < HID / 4; ++kk) {
            float4 av = as4[kk];  // wave-uniform broadcast ds_read_b128
            acc0 = fmaf(av.x, w[4 * kk + 0], acc0);
            acc1 = fmaf(av.y, w[4 * kk + 1], acc1);
            acc2 = fmaf(av.z, w[4 * kk + 2], acc2);
            acc3 = fmaf(av.w, w[4 * kk + 3], acc3);
        }
        float v = ((acc0 + acc1) + (acc2 + acc3)) + b;
        int r = row0 + rr;
        if (FUSE_OUT) v = fmaxf(v, 0.f) + xres[(size_t)r * HID + col];
        out[(size_t)r * HID + col] = v;
        if (BN_STATS) {
            double vd = (double)v;
            s0 += vd;
            s1 = fma(vd, vd, s1);
        }
    }

    if (BN_STATS) {
        // cross-wave reduce in LDS (reuse As), then 1 atomic per col per block
        __syncthreads();  // everyone done reading As
        double* sd = reinterpret_cast<double*>(As);
        sd[wid * 64 + lane] = s0;
        sd[256 + wid * 64 + lane] = s1;
        __syncthreads();
        if (wid == 0) {
            double t0 = (sd[lane] + sd[64 + lane]) + (sd[128 + lane] + sd[192 + lane]);
            double t1 = (sd[256 + lane] + sd[320 + lane]) + (sd[384 + lane] + sd[448 + lane]);
            atomicAdd(&bn_sum[col], t0);
            atomicAdd(&bn_sq[col], t1);
        }
    }
}

// ---------------- BN finalize: scale/shift per channel; self-zero stats for next layer ----
__global__ void k_bnfinal(double* __restrict__ sum, double* __restrict__ sq,
                          const float* __restrict__ gamma, const float* __restrict__ beta,
                          float* __restrict__ scale, float* __restrict__ shift, double inv_n) {
    int c = threadIdx.x;
    double m = sum[c] * inv_n;
    double var = sq[c] * inv_n - m * m;
    float sc = gamma[c] * rsqrtf((float)var + 1e-5f);
    scale[c] = sc;
    shift[c] = beta[c] - (float)m * sc;
    sum[c] = 0.0;
    sq[c] = 0.0;
}

// ---------------- global_add_pool over sorted batch (int32) ----------------
__global__ void k_pool(const float* __restrict__ xf, const int* __restrict__ batch,
                       float* __restrict__ pooled, int n) {
    int g = blockIdx.x;
    int lo = 0, hi = n;
    while (lo < hi) { int mid = (lo + hi) >> 1; if (batch[mid] < g) lo = mid + 1; else hi = mid; }
    int beg = lo;
    lo = 0; hi = n;
    int g1 = g + 1;
    while (lo < hi) { int mid = (lo + hi) >> 1; if (batch[mid] < g1) lo = mid + 1; else hi = mid; }
    int end = lo;
    int t = threadIdx.x;
    float a0 = 0.f, a1 = 0.f, a2 = 0.f, a3 = 0.f;
    int r = beg;
    for (; r + 4 <= end; r += 4) {
        a0 += xf[(size_t)(r + 0) * HID + t];
        a1 += xf[(size_t)(r + 1) * HID + t];
        a2 += xf[(size_t)(r + 2) * HID + t];
        a3 += xf[(size_t)(r + 3) * HID + t];
    }
    for (; r < end; ++r) a0 += xf[(size_t)r * HID + t];
    pooled[(size_t)blockIdx.x * HID + t] = (a0 + a1) + (a2 + a3);
}

extern "C" void kernel_launch(void* const* d_in, const int* in_sizes, int n_in,
                              void* d_out, int out_size, void* d_ws, size_t ws_size,
                              hipStream_t stream) {
    const float* x      = (const float*)d_in[0];
    const int* ei       = (const int*)d_in[1];   // int32 per harness contract
    const int* batch    = (const int*)d_in[2];   // int32
    const float* W1     = (const float*)d_in[3];
    const float* b1     = (const float*)d_in[4];
    const float* gamma  = (const float*)d_in[5];
    const float* beta   = (const float*)d_in[6];
    const float* W2     = (const float*)d_in[7];
    const float* b2     = (const float*)d_in[8];

    const int N = in_sizes[0] / HID;
    const int E = in_sizes[1] / 2;
    const int L = in_sizes[3] / (HID * HID);
    const int G = (out_size - N * HID) / HID;

    const int* esrc = ei;
    const int* edst = ei + E;

    char* ws = (char*)d_ws;
    size_t off = 0;
    auto alloc = [&](size_t bytes) {
        void* p = ws + off;
        off += (bytes + 255) & ~(size_t)255;
        return p;
    };
    float* bufA = (float*)alloc((size_t)N * HID * 4);
    float* bufh = (float*)alloc((size_t)N * HID * 4);
    int* deg = (int*)alloc((size_t)N * 4);
    int* rs  = (int*)alloc(((size_t)N + 1) * 4);
    int* cur = (int*)alloc((size_t)N * 4);
    int* csr = (int*)alloc((size_t)E * 4);
    int* partials   = (int*)alloc(256 * 4);
    double* bn_sum  = (double*)alloc(HID * 8);
    double* bn_sq   = (double*)alloc(HID * 8);
    float* bn_scale = (float*)alloc(HID * 4);
    float* bn_shift = (float*)alloc(HID * 4);
    (void)ws_size;  // ~110MB

    float* xout   = (float*)d_out;
    float* pooled = (float*)d_out + (size_t)N * HID;
    float* bufB   = xout;  // d_out node region doubles as ping-pong scratch

    const int NB = (N + SB - 1) / SB;        // 98 <= 256
    const int NWIN = (N + 7) / 8;            // dst window per XCD class

    // CSR by destination (rebuilt every call; identical work each call)
    hipMemsetAsync(deg, 0, (size_t)N * 4, stream);
    hipMemsetAsync(bn_sum, 0, HID * 8, stream);
    hipMemsetAsync(bn_sq, 0, HID * 8, stream);
    k_hist<<<(E + 255) / 256, 256, 0, stream>>>(edst, deg, E);
    k_scan1<<<NB, SB, 0, stream>>>(deg, rs, partials, N);
    k_scan2<<<1, 256, 0, stream>>>(partials, rs, NB, N);
    k_scan3<<<NB, SB, 0, stream>>>(rs, cur, partials, N);
    k_scatter<<<2048, 256, 0, stream>>>(esrc, edst, cur, csr, E, NWIN);

    // Buffer schedule (L=4): agg alternates A, B(=d_out), A, B; last layer's GEMM2
    // writes xout (same region as its agg — agg already consumed by GEMM1).
    dim3 ggrid((N + 63) / 64, 2);
    const float* xl = x;
    for (int l = 0; l < L; ++l) {
        float* agg  = (l & 1) ? bufB : bufA;
        float* outb = (l == L - 1) ? xout : agg;

        k_gather<<<(N * 64 + 255) / 256, 256, 0, stream>>>(xl, rs, csr, agg, N);

        k_gemm<true, false, false><<<ggrid, 256, 0, stream>>>(
            agg, W1 + (size_t)l * HID * HID, b1 + (size_t)l * HID, bufh,
            nullptr, nullptr, nullptr, bn_sum, bn_sq, N);
        k_bnfinal<<<1, HID, 0, stream>>>(bn_sum, bn_sq, gamma + (size_t)l * HID,
                                         beta + (size_t)l * HID, bn_scale, bn_shift,
                                         1.0 / (double)N);
        k_gemm<false, true, true><<<ggrid, 256, 0, stream>>>(
            bufh, W2 + (size_t)l * HID * HID, b2 + (size_t)l * HID, outb,
            xl, bn_scale, bn_shift, nullptr, nullptr, N);
        xl = outb;
    }

    k_pool<<<G, HID, 0, stream>>>(xout, batch, pooled, N);
}

// Round 7
// 1365.702 us; speedup vs baseline: 1.8538x; 1.8538x over previous
//
#include <hip/hip_runtime.h>

#define HID 128
#define SB 1024

// Harness contract: integer inputs arrive as int32 (int64 cast = R3 core dump).
// R6 lesson: a per-lane float w[128] spills (VGPR capped at 128; WRITE_SIZE
// showed 325MB of spill stores). GEMM must use LDS tiles + small register tiles.

// ---------------- CSR build ----------------
__global__ void k_hist(const int* __restrict__ dst, int* __restrict__ deg, int e) {
    int i = blockIdx.x * blockDim.x + threadIdx.x;
    if (i < e) atomicAdd(&deg[dst[i]], 1);
}

__global__ __launch_bounds__(SB)
void k_scan1(const int* __restrict__ deg, int* __restrict__ rs,
             int* __restrict__ partials, int n) {
    __shared__ int sh[SB];
    int t = threadIdx.x;
    int i = blockIdx.x * SB + t;
    int v = (i < n) ? deg[i] : 0;
    sh[t] = v;
    __syncthreads();
    for (int off = 1; off < SB; off <<= 1) {
        int add = (t >= off) ? sh[t - off] : 0;
        __syncthreads();
        sh[t] += add;
        __syncthreads();
    }
    if (i < n) rs[i] = sh[t] - v;
    if (t == SB - 1) partials[blockIdx.x] = sh[t];
}

__global__ __launch_bounds__(256)
void k_scan2(int* __restrict__ partials, int* __restrict__ rs, int nb, int n) {
    __shared__ int sh[256];
    int t = threadIdx.x;
    int v = (t < nb) ? partials[t] : 0;
    sh[t] = v;
    __syncthreads();
    for (int off = 1; off < 256; off <<= 1) {
        int add = (t >= off) ? sh[t - off] : 0;
        __syncthreads();
        sh[t] += add;
        __syncthreads();
    }
    if (t < nb) partials[t] = sh[t] - v;
    if (t == 255) rs[n] = sh[t];
}

__global__ __launch_bounds__(SB)
void k_scan3(int* __restrict__ rs, int* __restrict__ cur,
             const int* __restrict__ partials, int n) {
    int i = blockIdx.x * SB + threadIdx.x;
    if (i < n) {
        int v = rs[i] + partials[blockIdx.x];
        rs[i] = v;
        cur[i] = v;
    }
}

// XCD-windowed scatter (R5 fix for 16x partial-line write amplification)
__global__ __launch_bounds__(256)
void k_scatter(const int* __restrict__ src, const int* __restrict__ dst,
               int* __restrict__ cur, int* __restrict__ csr, int e, int nwin) {
    int p = blockIdx.x & 7;
    int slot = blockIdx.x >> 3;
    int nslots = gridDim.x >> 3;
    int lo = p * nwin, hi = lo + nwin;
    int stride = nslots * blockDim.x;
    for (int i = slot * blockDim.x + threadIdx.x; i < e; i += stride) {
        int d = dst[i];
        if (d >= lo && d < hi) {
            int pos = atomicAdd(&cur[d], 1);
            csr[pos] = src[i];
        }
    }
}

// ---------------- gather-aggregate: agg[i] = x[i] + sum_{j in CSR[i]} x[j] ----------------
__global__ __launch_bounds__(256)
void k_gather(const float* __restrict__ x, const int* __restrict__ rs,
              const int* __restrict__ csr, float* __restrict__ agg, int n) {
    int wave = (blockIdx.x * blockDim.x + threadIdx.x) >> 6;
    int lane = threadIdx.x & 63;
    if (wave >= n) return;
    int beg = rs[wave], end = rs[wave + 1];
    const float2* xp = reinterpret_cast<const float2*>(x);
    float2 acc = xp[(size_t)wave * 64 + lane];
    int j = beg;
    for (; j + 4 <= end; j += 4) {
        int s0 = csr[j], s1 = csr[j + 1], s2 = csr[j + 2], s3 = csr[j + 3];
        float2 v0 = xp[(size_t)s0 * 64 + lane];
        float2 v1 = xp[(size_t)s1 * 64 + lane];
        float2 v2 = xp[(size_t)s2 * 64 + lane];
        float2 v3 = xp[(size_t)s3 * 64 + lane];
        acc.x += (v0.x + v1.x) + (v2.x + v3.x);
        acc.y += (v0.y + v1.y) + (v2.y + v3.y);
    }
    for (; j < end; ++j) {
        int s = csr[j];
        float2 v = xp[(size_t)s * 64 + lane];
        acc.x += v.x;
        acc.y += v.y;
    }
    reinterpret_cast<float2*>(agg)[(size_t)wave * 64 + lane] = acc;
}

// ---------------- register-blocked fp32 GEMM ----------------
// out[r][c] = A[r][:] . W[:][c] + bias[c].  Grid: (ceil(N/64), 2 column halves).
// Block 256 thr = 16x16 (ty,tx); thread computes 4x4 outputs (rows ty+16*rm,
// cols cbase+tx+16*cn). K processed in two BK=64 halves; per half: A-tile 64x64
// and W^T-tile 64x64 staged in LDS with stride 68 (pad -> a-frag reads are 4
// broadcast addrs, b-frag reads 2-way = free). LDS 34.8KB -> 4 blocks/CU.
// BN_LOAD: BN+ReLU applied while staging A (== old bnapply, bit-identical).
// BN_STATS: f64 per-col partials -> LDS reduce -> 2 atomics/col/block.
// FUSE_OUT: out = relu(acc+bias) + xres.
#define LDW 68
#define LDW4 17
template <bool BN_STATS, bool BN_LOAD, bool FUSE_OUT>
__global__ __launch_bounds__(256)
void k_gemm(const float* __restrict__ A, const float* __restrict__ W,
            const float* __restrict__ bias, float* __restrict__ out,
            const float* __restrict__ xres,
            const float* __restrict__ bn_scale, const float* __restrict__ bn_shift,
            double* __restrict__ bn_sum, double* __restrict__ bn_sq, int nrows) {
    __shared__ __align__(16) float As[64 * LDW];
    __shared__ __align__(16) float Ws[64 * LDW];
    int t = threadIdx.x;
    int tx = t & 15, ty = t >> 4;
    int row0 = blockIdx.x * 64;
    int cbase = blockIdx.y * 64;
    int nr = min(64, nrows - row0);
    int maxv = nr * 16;  // valid float4 count per K-half

    float acc[4][4] = {};

    for (int kh = 0; kh < 2; ++kh) {
        if (kh) __syncthreads();  // prev compute done before restage
        // stage A half-tile: rows row0..+63, k = kh*64..+63  (+BN+ReLU if BN_LOAD)
        {
            const float4* sc4 = reinterpret_cast<const float4*>(bn_scale);
            const float4* sh4 = reinterpret_cast<const float4*>(bn_shift);
            float4* s4 = reinterpret_cast<float4*>(As);
#pragma unroll
            for (int i = 0; i < 4; ++i) {
                int idx = t + 256 * i;        // 0..1023
                int row = idx >> 4, c4 = idx & 15;
                float4 v = make_float4(0.f, 0.f, 0.f, 0.f);
                if (idx < maxv) {
                    v = *reinterpret_cast<const float4*>(
                        A + (size_t)(row0 + row) * HID + kh * 64 + c4 * 4);
                    if (BN_LOAD) {
                        float4 a = sc4[kh * 16 + c4], bb = sh4[kh * 16 + c4];
                        v.x = fmaxf(fmaf(v.x, a.x, bb.x), 0.f);
                        v.y = fmaxf(fmaf(v.y, a.y, bb.y), 0.f);
                        v.z = fmaxf(fmaf(v.z, a.z, bb.z), 0.f);
                        v.w = fmaxf(fmaf(v.w, a.w, bb.w), 0.f);
                    }
                }
                s4[row * LDW4 + c4] = v;
            }
        }
        // stage W^T half: Ws[c'][kk] = W[kh*64+kk][cbase+c']
        {
#pragma unroll
            for (int i = 0; i < 4; ++i) {
                int idx = t + 256 * i;        // 0..1023
                int kk = idx >> 4, c4 = idx & 15;
                float4 v = *reinterpret_cast<const float4*>(
                    W + (size_t)(kh * 64 + kk) * HID + cbase + c4 * 4);
                Ws[(c4 * 4 + 0) * LDW + kk] = v.x;
                Ws[(c4 * 4 + 1) * LDW + kk] = v.y;
                Ws[(c4 * 4 + 2) * LDW + kk] = v.z;
                Ws[(c4 * 4 + 3) * LDW + kk] = v.w;
            }
        }
        __syncthreads();

        const float4* As4 = reinterpret_cast<const float4*>(As);
        const float4* Ws4 = reinterpret_cast<const float4*>(Ws);
#pragma unroll 4
        for (int k4 = 0; k4 < 16; ++k4) {
            float4 af[4], bf[4];
#pragma unroll
            for (int rm = 0; rm < 4; ++rm) af[rm] = As4[(ty + 16 * rm) * LDW4 + k4];
#pragma unroll
            for (int cn = 0; cn < 4; ++cn) bf[cn] = Ws4[(tx + 16 * cn) * LDW4 + k4];
#pragma unroll
            for (int rm = 0; rm < 4; ++rm)
#pragma unroll
                for (int cn = 0; cn < 4; ++cn) {
                    acc[rm][cn] = fmaf(af[rm].x, bf[cn].x, acc[rm][cn]);
                    acc[rm][cn] = fmaf(af[rm].y, bf[cn].y, acc[rm][cn]);
                    acc[rm][cn] = fmaf(af[rm].z, bf[cn].z, acc[rm][cn]);
                    acc[rm][cn] = fmaf(af[rm].w, bf[cn].w, acc[rm][cn]);
                }
        }
    }

    // epilogue
    float bv[4];
#pragma unroll
    for (int cn = 0; cn < 4; ++cn) bv[cn] = bias[cbase + tx + 16 * cn];

    double sc0[4] = {0.0, 0.0, 0.0, 0.0}, sc1[4] = {0.0, 0.0, 0.0, 0.0};
#pragma unroll
    for (int rm = 0; rm < 4; ++rm) {
        int rr = ty + 16 * rm;
        if (rr < nr) {
            size_t r = (size_t)(row0 + rr);
#pragma unroll
            for (int cn = 0; cn < 4; ++cn) {
                int c = cbase + tx + 16 * cn;
                float v = acc[rm][cn] + bv[cn];
                if (FUSE_OUT) v = fmaxf(v, 0.f) + xres[r * HID + c];
                out[r * HID + c] = v;
                if (BN_STATS) {
                    double vd = (double)v;
                    sc0[cn] += vd;
                    sc1[cn] = fma(vd, vd, sc1[cn]);
                }
            }
        }
    }

    if (BN_STATS) {
        __syncthreads();  // done reading As/Ws
        double* dsum = reinterpret_cast<double*>(As);   // [64 cols][16 ty]
        double* dsq  = dsum + 1024;
#pragma unroll
        for (int cn = 0; cn < 4; ++cn) {
            dsum[(tx + 16 * cn) * 16 + ty] = sc0[cn];
            dsq[(tx + 16 * cn) * 16 + ty]  = sc1[cn];
        }
        __syncthreads();
        if (t < 64) {
            double a = 0.0, b = 0.0;
#pragma unroll
            for (int y = 0; y < 16; ++y) {
                a += dsum[t * 16 + y];
                b += dsq[t * 16 + y];
            }
            atomicAdd(&bn_sum[cbase + t], a);
            atomicAdd(&bn_sq[cbase + t], b);
        }
    }
}

// ---------------- BN finalize; self-zero stats for next layer ----------------
__global__ void k_bnfinal(double* __restrict__ sum, double* __restrict__ sq,
                          const float* __restrict__ gamma, const float* __restrict__ beta,
                          float* __restrict__ scale, float* __restrict__ shift, double inv_n) {
    int c = threadIdx.x;
    double m = sum[c] * inv_n;
    double var = sq[c] * inv_n - m * m;
    float sc = gamma[c] * rsqrtf((float)var + 1e-5f);
    scale[c] = sc;
    shift[c] = beta[c] - (float)m * sc;
    sum[c] = 0.0;
    sq[c] = 0.0;
}

// ---------------- global_add_pool over sorted batch (int32) ----------------
__global__ void k_pool(const float* __restrict__ xf, const int* __restrict__ batch,
                       float* __restrict__ pooled, int n) {
    int g = blockIdx.x;
    int lo = 0, hi = n;
    while (lo < hi) { int mid = (lo + hi) >> 1; if (batch[mid] < g) lo = mid + 1; else hi = mid; }
    int beg = lo;
    lo = 0; hi = n;
    int g1 = g + 1;
    while (lo < hi) { int mid = (lo + hi) >> 1; if (batch[mid] < g1) lo = mid + 1; else hi = mid; }
    int end = lo;
    int t = threadIdx.x;
    float a0 = 0.f, a1 = 0.f, a2 = 0.f, a3 = 0.f;
    int r = beg;
    for (; r + 4 <= end; r += 4) {
        a0 += xf[(size_t)(r + 0) * HID + t];
        a1 += xf[(size_t)(r + 1) * HID + t];
        a2 += xf[(size_t)(r + 2) * HID + t];
        a3 += xf[(size_t)(r + 3) * HID + t];
    }
    for (; r < end; ++r) a0 += xf[(size_t)r * HID + t];
    pooled[(size_t)blockIdx.x * HID + t] = (a0 + a1) + (a2 + a3);
}

extern "C" void kernel_launch(void* const* d_in, const int* in_sizes, int n_in,
                              void* d_out, int out_size, void* d_ws, size_t ws_size,
                              hipStream_t stream) {
    const float* x      = (const float*)d_in[0];
    const int* ei       = (const int*)d_in[1];
    const int* batch    = (const int*)d_in[2];
    const float* W1     = (const float*)d_in[3];
    const float* b1     = (const float*)d_in[4];
    const float* gamma  = (const float*)d_in[5];
    const float* beta   = (const float*)d_in[6];
    const float* W2     = (const float*)d_in[7];
    const float* b2     = (const float*)d_in[8];

    const int N = in_sizes[0] / HID;
    const int E = in_sizes[1] / 2;
    const int L = in_sizes[3] / (HID * HID);
    const int G = (out_size - N * HID) / HID;

    const int* esrc = ei;
    const int* edst = ei + E;

    char* ws = (char*)d_ws;
    size_t off = 0;
    auto alloc = [&](size_t bytes) {
        void* p = ws + off;
        off += (bytes + 255) & ~(size_t)255;
        return p;
    };
    float* bufA = (float*)alloc((size_t)N * HID * 4);
    float* bufh = (float*)alloc((size_t)N * HID * 4);
    int* deg = (int*)alloc((size_t)N * 4);
    int* rs  = (int*)alloc(((size_t)N + 1) * 4);
    int* cur = (int*)alloc((size_t)N * 4);
    int* csr = (int*)alloc((size_t)E * 4);
    int* partials   = (int*)alloc(256 * 4);
    double* bn_sum  = (double*)alloc(HID * 8);
    double* bn_sq   = (double*)alloc(HID * 8);
    float* bn_scale = (float*)alloc(HID * 4);
    float* bn_shift = (float*)alloc(HID * 4);
    (void)ws_size;  // ~110MB

    float* xout   = (float*)d_out;
    float* pooled = (float*)d_out + (size_t)N * HID;
    float* bufB   = xout;  // d_out node region doubles as ping-pong scratch

    const int NB = (N + SB - 1) / SB;
    const int NWIN = (N + 7) / 8;

    hipMemsetAsync(deg, 0, (size_t)N * 4, stream);
    hipMemsetAsync(bn_sum, 0, HID * 8, stream);
    hipMemsetAsync(bn_sq, 0, HID * 8, stream);
    k_hist<<<(E + 255) / 256, 256, 0, stream>>>(edst, deg, E);
    k_scan1<<<NB, SB, 0, stream>>>(deg, rs, partials, N);
    k_scan2<<<1, 256, 0, stream>>>(partials, rs, NB, N);
    k_scan3<<<NB, SB, 0, stream>>>(rs, cur, partials, N);
    k_scatter<<<2048, 256, 0, stream>>>(esrc, edst, cur, csr, E, NWIN);

    dim3 ggrid((N + 63) / 64, 2);
    const float* xl = x;
    for (int l = 0; l < L; ++l) {
        float* agg  = (l & 1) ? bufB : bufA;
        float* outb = (l == L - 1) ? xout : agg;

        k_gather<<<(N * 64 + 255) / 256, 256, 0, stream>>>(xl, rs, csr, agg, N);

        k_gemm<true, false, false><<<ggrid, 256, 0, stream>>>(
            agg, W1 + (size_t)l * HID * HID, b1 + (size_t)l * HID, bufh,
            nullptr, nullptr, nullptr, bn_sum, bn_sq, N);
        k_bnfinal<<<1, HID, 0, stream>>>(bn_sum, bn_sq, gamma + (size_t)l * HID,
                                         beta + (size_t)l * HID, bn_scale, bn_shift,
                                         1.0 / (double)N);
        k_gemm<false, true, true><<<ggrid, 256, 0, stream>>>(
            bufh, W2 + (size_t)l * HID * HID, b2 + (size_t)l * HID, outb,
            xl, bn_scale, bn_shift, nullptr, nullptr, N);
        xl = outb;
    }

    k_pool<<<G, HID, 0, stream>>>(xout, batch, pooled, N);
}

// Round 8
// 1263.731 us; speedup vs baseline: 2.0034x; 1.0807x over previous
//
#include <hip/hip_runtime.h>

#define HID 128
#define SB 1024
#define LDA 136   // bf16 plane row stride (shorts); 272B = 16B-aligned rows

// Harness contract: integer inputs arrive as int32 (int64 cast = R3 core dump).
// R6 lesson: no big per-lane arrays (w[128] spilled: 325MB WRITE_SIZE).
// R7 lesson: VALU GEMM is LDS-BW-bound (~1B/FLOP); MFMA bf16-split is 8x better.

__device__ __forceinline__ unsigned short bf16h(float x) {
    unsigned int u = __float_as_uint(x);
    return (unsigned short)((u + 0x7fffu + ((u >> 16) & 1u)) >> 16);  // RNE
}
__device__ __forceinline__ float bf16f(unsigned short h) {
    return __uint_as_float(((unsigned int)h) << 16);
}

using bfrag = __attribute__((ext_vector_type(8))) short;   // 8 bf16 = 4 VGPR
using f32x4v = __attribute__((ext_vector_type(4))) float;  // C/D frag

// ---------------- CSR build ----------------
__global__ void k_hist(const int* __restrict__ dst, int* __restrict__ deg, int e) {
    int i = blockIdx.x * blockDim.x + threadIdx.x;
    if (i < e) atomicAdd(&deg[dst[i]], 1);
}

__global__ __launch_bounds__(SB)
void k_scan1(const int* __restrict__ deg, int* __restrict__ rs,
             int* __restrict__ partials, int n) {
    __shared__ int sh[SB];
    int t = threadIdx.x;
    int i = blockIdx.x * SB + t;
    int v = (i < n) ? deg[i] : 0;
    sh[t] = v;
    __syncthreads();
    for (int off = 1; off < SB; off <<= 1) {
        int add = (t >= off) ? sh[t - off] : 0;
        __syncthreads();
        sh[t] += add;
        __syncthreads();
    }
    if (i < n) rs[i] = sh[t] - v;
    if (t == SB - 1) partials[blockIdx.x] = sh[t];
}

__global__ __launch_bounds__(256)
void k_scan2(int* __restrict__ partials, int* __restrict__ rs, int nb, int n) {
    __shared__ int sh[256];
    int t = threadIdx.x;
    int v = (t < nb) ? partials[t] : 0;
    sh[t] = v;
    __syncthreads();
    for (int off = 1; off < 256; off <<= 1) {
        int add = (t >= off) ? sh[t - off] : 0;
        __syncthreads();
        sh[t] += add;
        __syncthreads();
    }
    if (t < nb) partials[t] = sh[t] - v;
    if (t == 255) rs[n] = sh[t];
}

__global__ __launch_bounds__(SB)
void k_scan3(int* __restrict__ rs, int* __restrict__ cur,
             const int* __restrict__ partials, int n) {
    int i = blockIdx.x * SB + threadIdx.x;
    if (i < n) {
        int v = rs[i] + partials[blockIdx.x];
        rs[i] = v;
        cur[i] = v;
    }
}

// XCD-windowed scatter (R5 fix for partial-line write amplification)
__global__ __launch_bounds__(256)
void k_scatter(const int* __restrict__ src, const int* __restrict__ dst,
               int* __restrict__ cur, int* __restrict__ csr, int e, int nwin) {
    int p = blockIdx.x & 7;
    int slot = blockIdx.x >> 3;
    int nslots = gridDim.x >> 3;
    int lo = p * nwin, hi = lo + nwin;
    int stride = nslots * blockDim.x;
    for (int i = slot * blockDim.x + threadIdx.x; i < e; i += stride) {
        int d = dst[i];
        if (d >= lo && d < hi) {
            int pos = atomicAdd(&cur[d], 1);
            csr[pos] = src[i];
        }
    }
}

// ---------------- gather-aggregate: agg[i] = x[i] + sum_{j in CSR[i]} x[j] ----------------
__global__ __launch_bounds__(256)
void k_gather(const float* __restrict__ x, const int* __restrict__ rs,
              const int* __restrict__ csr, float* __restrict__ agg, int n) {
    int wave = (blockIdx.x * blockDim.x + threadIdx.x) >> 6;
    int lane = threadIdx.x & 63;
    if (wave >= n) return;
    int beg = rs[wave], end = rs[wave + 1];
    const float2* xp = reinterpret_cast<const float2*>(x);
    float2 acc = xp[(size_t)wave * 64 + lane];
    int j = beg;
    for (; j + 8 <= end; j += 8) {  // 8 loads in flight (latency-bound at 47% BW)
        int s0 = csr[j], s1 = csr[j + 1], s2 = csr[j + 2], s3 = csr[j + 3];
        int s4 = csr[j + 4], s5 = csr[j + 5], s6 = csr[j + 6], s7 = csr[j + 7];
        float2 v0 = xp[(size_t)s0 * 64 + lane];
        float2 v1 = xp[(size_t)s1 * 64 + lane];
        float2 v2 = xp[(size_t)s2 * 64 + lane];
        float2 v3 = xp[(size_t)s3 * 64 + lane];
        float2 v4 = xp[(size_t)s4 * 64 + lane];
        float2 v5 = xp[(size_t)s5 * 64 + lane];
        float2 v6 = xp[(size_t)s6 * 64 + lane];
        float2 v7 = xp[(size_t)s7 * 64 + lane];
        acc.x += ((v0.x + v1.x) + (v2.x + v3.x)) + ((v4.x + v5.x) + (v6.x + v7.x));
        acc.y += ((v0.y + v1.y) + (v2.y + v3.y)) + ((v4.y + v5.y) + (v6.y + v7.y));
    }
    for (; j < end; ++j) {
        int s = csr[j];
        float2 v = xp[(size_t)s * 64 + lane];
        acc.x += v.x;
        acc.y += v.y;
    }
    reinterpret_cast<float2*>(agg)[(size_t)wave * 64 + lane] = acc;
}

// ---------------- W pre-pack: per-fragment bf16 hi/lo planes ----------------
// Pack index e = ((kc*128 + c)*4 + g)*8 + j  <->  k = kc*32 + g*8 + j.
// B-frag load in GEMM = one 16B load at frag index (kc*128+c)*4+g.
__global__ __launch_bounds__(256)
void k_wpack(const float* __restrict__ W1, const float* __restrict__ W2,
             short* __restrict__ wph, short* __restrict__ wpl) {
    int m = blockIdx.x >> 3;          // matrix 0..7 (W1[0..3], W2[0..3])
    int part = blockIdx.x & 7;        // 2048-elem slice
    const float* src = (m < 4) ? (W1 + (size_t)m * 16384) : (W2 + (size_t)(m - 4) * 16384);
    for (int i = 0; i < 8; ++i) {
        int e = part * 2048 + threadIdx.x + 256 * i;
        int j = e & 7, g = (e >> 3) & 3, c = (e >> 5) & 127, kc = e >> 12;
        int k = kc * 32 + g * 8 + j;
        float v = src[k * 128 + c];
        unsigned short h = bf16h(v);
        unsigned short l = bf16h(v - bf16f(h));
        wph[(size_t)m * 16384 + e] = (short)h;
        wpl[(size_t)m * 16384 + e] = (short)l;
    }
}

// ---------------- bf16-split MFMA GEMM: out = A @ W + bias ----------------
// Grid: ceil(N/64) blocks; block = 256 thr = 4 waves; wave w owns rows [w*16,w*16+16).
// A staged to LDS as bf16 hi/lo planes (fp32 read -> split; BN+ReLU on load if BN_LOAD).
// Per (kc, ctile): 3 MFMA (ah*wh, ah*wl, al*wh), fp32 accum. C/D layout (verified):
// col = lane&15, row = (lane>>4)*4 + reg. A-frag: row=lane&15, k=kc*32+(lane>>4)*8+j;
// B-frag same k convention (pack above) -> any k-permutation error cancels (sigmaA=sigmaB).
template <bool BN_STATS, bool BN_LOAD, bool FUSE_OUT>
__global__ __launch_bounds__(256, 4)
void k_gemm(const float* __restrict__ A, const short* __restrict__ WBh,
            const short* __restrict__ WBl, const float* __restrict__ bias,
            float* __restrict__ out, const float* __restrict__ xres,
            const float* __restrict__ bn_scale, const float* __restrict__ bn_shift,
            double* __restrict__ bn_sum, double* __restrict__ bn_sq, int nrows) {
    __shared__ __align__(16) short Ah[64 * LDA];
    __shared__ __align__(16) short Al[64 * LDA];
    int t = threadIdx.x;
    int w = t >> 6, lane = t & 63;
    int row0 = blockIdx.x * 64;
    int nr = min(64, nrows - row0);

    // ---- stage A: 64 rows x 128 cols fp32 -> bf16 hi/lo planes ----
    {
        const float4* sc4 = reinterpret_cast<const float4*>(bn_scale);
        const float4* sh4 = reinterpret_cast<const float4*>(bn_shift);
#pragma unroll
        for (int i = 0; i < 8; ++i) {
            int idx = t + 256 * i;          // 0..2047 float4 slots
            int row = idx >> 5;
            int c4 = (idx & 31) * 4;
            float4 v = make_float4(0.f, 0.f, 0.f, 0.f);
            if (row < nr) {
                v = *reinterpret_cast<const float4*>(A + (size_t)(row0 + row) * HID + c4);
                if (BN_LOAD) {
                    float4 a = sc4[idx & 31], bb = sh4[idx & 31];
                    v.x = fmaxf(fmaf(v.x, a.x, bb.x), 0.f);
                    v.y = fmaxf(fmaf(v.y, a.y, bb.y), 0.f);
                    v.z = fmaxf(fmaf(v.z, a.z, bb.z), 0.f);
                    v.w = fmaxf(fmaf(v.w, a.w, bb.w), 0.f);
                }
            }
            unsigned short h0 = bf16h(v.x), h1 = bf16h(v.y), h2 = bf16h(v.z), h3 = bf16h(v.w);
            short4 hv = make_short4((short)h0, (short)h1, (short)h2, (short)h3);
            short4 lv = make_short4((short)bf16h(v.x - bf16f(h0)), (short)bf16h(v.y - bf16f(h1)),
                                    (short)bf16h(v.z - bf16f(h2)), (short)bf16h(v.w - bf16f(h3)));
            *reinterpret_cast<short4*>(&Ah[row * LDA + c4]) = hv;
            *reinterpret_cast<short4*>(&Al[row * LDA + c4]) = lv;
        }
    }
    __syncthreads();

    int arow = lane & 15, ag = lane >> 4;
    const bfrag* WH = reinterpret_cast<const bfrag*>(WBh);
    const bfrag* WL = reinterpret_cast<const bfrag*>(WBl);

    f32x4v acc[8];
#pragma unroll
    for (int ct = 0; ct < 8; ++ct) acc[ct] = (f32x4v){0.f, 0.f, 0.f, 0.f};

#pragma unroll
    for (int kc = 0; kc < 4; ++kc) {
        int aoff = (w * 16 + arow) * LDA + kc * 32 + ag * 8;
        bfrag ah = *reinterpret_cast<const bfrag*>(&Ah[aoff]);
        bfrag al = *reinterpret_cast<const bfrag*>(&Al[aoff]);
#pragma unroll
        for (int ct = 0; ct < 8; ++ct) {
            int widx = (kc * 128 + ct * 16 + arow) * 4 + ag;
            bfrag bh = WH[widx];
            bfrag bl = WL[widx];
            acc[ct] = __builtin_amdgcn_mfma_f32_16x16x32_bf16(ah, bh, acc[ct], 0, 0, 0);
            acc[ct] = __builtin_amdgcn_mfma_f32_16x16x32_bf16(ah, bl, acc[ct], 0, 0, 0);
            acc[ct] = __builtin_amdgcn_mfma_f32_16x16x32_bf16(al, bh, acc[ct], 0, 0, 0);
        }
    }

    // ---- epilogue: bias (+relu+residual) store; BN stats reduce ----
    double s0[8], s1[8];
#pragma unroll
    for (int ct = 0; ct < 8; ++ct) {
        int c = ct * 16 + arow;
        float bv = bias[c];
        double a0 = 0.0, a1 = 0.0;
#pragma unroll
        for (int reg = 0; reg < 4; ++reg) {
            int rl = w * 16 + ag * 4 + reg;   // local row (C/D layout)
            if (rl < nr) {
                size_t r = (size_t)(row0 + rl);
                float v = acc[ct][reg] + bv;
                if (FUSE_OUT) v = fmaxf(v, 0.f) + xres[r * HID + c];
                out[r * HID + c] = v;
                if (BN_STATS) {
                    double vd = (double)v;
                    a0 += vd;
                    a1 = fma(vd, vd, a1);
                }
            }
        }
        s0[ct] = a0;
        s1[ct] = a1;
    }

    if (BN_STATS) {
        __syncthreads();  // done reading Ah/Al -> reuse as reduce scratch
        double* rsum = reinterpret_cast<double*>(Ah);  // [4 waves][128 cols]
        double* rsq  = reinterpret_cast<double*>(Al);
#pragma unroll
        for (int ct = 0; ct < 8; ++ct) {
            double a0 = s0[ct], a1 = s1[ct];
            a0 += __shfl_xor(a0, 16);
            a0 += __shfl_xor(a0, 32);
            a1 += __shfl_xor(a1, 16);
            a1 += __shfl_xor(a1, 32);
            if (lane < 16) {
                rsum[w * 128 + ct * 16 + lane] = a0;
                rsq[w * 128 + ct * 16 + lane] = a1;
            }
        }
        __syncthreads();
        if (t < 128) {
            double a = (rsum[t] + rsum[128 + t]) + (rsum[256 + t] + rsum[384 + t]);
            double b = (rsq[t] + rsq[128 + t]) + (rsq[256 + t] + rsq[384 + t]);
            atomicAdd(&bn_sum[t], a);
            atomicAdd(&bn_sq[t], b);
        }
    }
}

// ---------------- BN finalize; self-zero stats for next layer ----------------
__global__ void k_bnfinal(double* __restrict__ sum, double* __restrict__ sq,
                          const float* __restrict__ gamma, const float* __restrict__ beta,
                          float* __restrict__ scale, float* __restrict__ shift, double inv_n) {
    int c = threadIdx.x;
    double m = sum[c] * inv_n;
    double var = sq[c] * inv_n - m * m;
    float sc = gamma[c] * rsqrtf((float)var + 1e-5f);
    scale[c] = sc;
    shift[c] = beta[c] - (float)m * sc;
    sum[c] = 0.0;
    sq[c] = 0.0;
}

// ---------------- global_add_pool over sorted batch (int32) ----------------
__global__ void k_pool(const float* __restrict__ xf, const int* __restrict__ batch,
                       float* __restrict__ pooled, int n) {
    int g = blockIdx.x;
    int lo = 0, hi = n;
    while (lo < hi) { int mid = (lo + hi) >> 1; if (batch[mid] < g) lo = mid + 1; else hi = mid; }
    int beg = lo;
    lo = 0; hi = n;
    int g1 = g + 1;
    while (lo < hi) { int mid = (lo + hi) >> 1; if (batch[mid] < g1) lo = mid + 1; else hi = mid; }
    int end = lo;
    int t = threadIdx.x;
    float a0 = 0.f, a1 = 0.f, a2 = 0.f, a3 = 0.f;
    int r = beg;
    for (; r + 4 <= end; r += 4) {
        a0 += xf[(size_t)(r + 0) * HID + t];
        a1 += xf[(size_t)(r + 1) * HID + t];
        a2 += xf[(size_t)(r + 2) * HID + t];
        a3 += xf[(size_t)(r + 3) * HID + t];
    }
    for (; r < end; ++r) a0 += xf[(size_t)r * HID + t];
    pooled[(size_t)blockIdx.x * HID + t] = (a0 + a1) + (a2 + a3);
}

extern "C" void kernel_launch(void* const* d_in, const int* in_sizes, int n_in,
                              void* d_out, int out_size, void* d_ws, size_t ws_size,
                              hipStream_t stream) {
    const float* x      = (const float*)d_in[0];
    const int* ei       = (const int*)d_in[1];
    const int* batch    = (const int*)d_in[2];
    const float* W1     = (const float*)d_in[3];
    const float* b1     = (const float*)d_in[4];
    const float* gamma  = (const float*)d_in[5];
    const float* beta   = (const float*)d_in[6];
    const float* W2     = (const float*)d_in[7];
    const float* b2     = (const float*)d_in[8];

    const int N = in_sizes[0] / HID;
    const int E = in_sizes[1] / 2;
    const int L = in_sizes[3] / (HID * HID);
    const int G = (out_size - N * HID) / HID;

    const int* esrc = ei;
    const int* edst = ei + E;

    char* ws = (char*)d_ws;
    size_t off = 0;
    auto alloc = [&](size_t bytes) {
        void* p = ws + off;
        off += (bytes + 255) & ~(size_t)255;
        return p;
    };
    float* bufA = (float*)alloc((size_t)N * HID * 4);
    float* bufh = (float*)alloc((size_t)N * HID * 4);
    int* deg = (int*)alloc((size_t)N * 4);
    int* rs  = (int*)alloc(((size_t)N + 1) * 4);
    int* cur = (int*)alloc((size_t)N * 4);
    int* csr = (int*)alloc((size_t)E * 4);
    int* partials   = (int*)alloc(256 * 4);
    double* bn_sum  = (double*)alloc(HID * 8);
    double* bn_sq   = (double*)alloc(HID * 8);
    float* bn_scale = (float*)alloc(HID * 4);
    float* bn_shift = (float*)alloc(HID * 4);
    short* wph = (short*)alloc((size_t)8 * 16384 * 2);  // packed bf16 hi (W1 x4, W2 x4)
    short* wpl = (short*)alloc((size_t)8 * 16384 * 2);  // packed bf16 lo
    (void)ws_size;  // ~111MB

    float* xout   = (float*)d_out;
    float* pooled = (float*)d_out + (size_t)N * HID;
    float* bufB   = xout;  // d_out node region doubles as ping-pong scratch

    const int NB = (N + SB - 1) / SB;
    const int NWIN = (N + 7) / 8;

    hipMemsetAsync(deg, 0, (size_t)N * 4, stream);
    hipMemsetAsync(bn_sum, 0, HID * 8, stream);
    hipMemsetAsync(bn_sq, 0, HID * 8, stream);
    k_wpack<<<64, 256, 0, stream>>>(W1, W2, wph, wpl);
    k_hist<<<(E + 255) / 256, 256, 0, stream>>>(edst, deg, E);
    k_scan1<<<NB, SB, 0, stream>>>(deg, rs, partials, N);
    k_scan2<<<1, 256, 0, stream>>>(partials, rs, NB, N);
    k_scan3<<<NB, SB, 0, stream>>>(rs, cur, partials, N);
    k_scatter<<<2048, 256, 0, stream>>>(esrc, edst, cur, csr, E, NWIN);

    const int GB = (N + 63) / 64;  // GEMM blocks
    const float* xl = x;
    for (int l = 0; l < L; ++l) {
        float* agg  = (l & 1) ? bufB : bufA;
        float* outb = (l == L - 1) ? xout : agg;
        const short* w1h = wph + (size_t)l * 16384;
        const short* w1l = wpl + (size_t)l * 16384;
        const short* w2h = wph + (size_t)(l + 4) * 16384;
        const short* w2l = wpl + (size_t)(l + 4) * 16384;

        k_gather<<<(N * 64 + 255) / 256, 256, 0, stream>>>(xl, rs, csr, agg, N);

        k_gemm<true, false, false><<<GB, 256, 0, stream>>>(
            agg, w1h, w1l, b1 + (size_t)l * HID, bufh,
            nullptr, nullptr, nullptr, bn_sum, bn_sq, N);
        k_bnfinal<<<1, HID, 0, stream>>>(bn_sum, bn_sq, gamma + (size_t)l * HID,
                                         beta + (size_t)l * HID, bn_scale, bn_shift,
                                         1.0 / (double)N);
        k_gemm<false, true, true><<<GB, 256, 0, stream>>>(
            bufh, w2h, w2l, b2 + (size_t)l * HID, outb,
            xl, bn_scale, bn_shift, nullptr, nullptr, N);
        xl = outb;
    }

    k_pool<<<G, HID, 0, stream>>>(xout, batch, pooled, N);
}